// Round 13
// baseline (271.519 us; speedup 1.0000x reference)
//
#include <hip/hip_runtime.h>

#define LATENT 128
#define HEAD 8
#define DH 16

#define SCAN_BLOCK 2048    // elements scanned per block
#define SCAN_THREADS 256   // 8 elements per thread

typedef __attribute__((ext_vector_type(8))) short short8;
typedef __attribute__((ext_vector_type(4))) float floatx4;

__device__ inline float bf2f(unsigned short u) {
    return __uint_as_float(((unsigned int)u) << 16);
}
__device__ inline unsigned short f2bf(float f) {
    unsigned int b = __float_as_uint(f);
    b += 0x7fffu + ((b >> 16) & 1u);          // RNE
    return (unsigned short)(b >> 16);
}

// ---------------------------------------------------------------------------
// Split W into bf16 hi/lo, transposed: Wt{hi,lo}[mat][c][k] from W[mat][k][c]
// ---------------------------------------------------------------------------
__global__ __launch_bounds__(256) void convert_wt(
    const float* __restrict__ Wq, const float* __restrict__ Wk, const float* __restrict__ Wv,
    unsigned short* __restrict__ Wthi, unsigned short* __restrict__ Wtlo)
{
    int idx = blockIdx.x * 256 + threadIdx.x;
    if (idx >= 3 * LATENT * LATENT) return;
    int mat = idx >> 14;
    int r   = idx & 16383;
    int c   = r >> 7;
    int k   = r & 127;
    const float* W = (mat == 0) ? Wq : ((mat == 1) ? Wk : Wv);
    float x = W[k * LATENT + c];
    unsigned short hi = f2bf(x);
    Wthi[idx] = hi;
    Wtlo[idx] = f2bf(x - bf2f(hi));
}

// ---------------------------------------------------------------------------
// Kernel 1: QKV projection, LDS-FREE split-bf16 MFMA.
// Grid (782, 3, 2): 64-row x 64-col tile (mat = y, col half = z).
// No LDS, no barriers: B fragments are read directly from global Wt (the
// 32 KB hi+lo panel is L1/L2-resident, shared by all 782 row-blocks), so
// the compiler pipelines A-load/split/MFMA freely and occupancy is
// VGPR-bound (~6 waves/SIMD) instead of LDS-bound (2 blocks/CU, 9.5% occ).
// Q,K: 3-term (fp32-accurate). V: 2-term. Output: Q fp32; K,V packed bf16.
// ---------------------------------------------------------------------------
__global__ __launch_bounds__(256) void qkv_gemm_reg(
    const float* __restrict__ emb,
    const unsigned short* __restrict__ Wthi, const unsigned short* __restrict__ Wtlo,
    float* __restrict__ Qf, unsigned short* __restrict__ KVb, int nNodes)
{
    const int mat  = blockIdx.y;
    const int ch   = blockIdx.z;                 // column half: 0 or 1
    const int row0 = blockIdx.x * 64;
    const int tid  = threadIdx.x;
    const int wid  = tid >> 6;
    const int lane = tid & 63;
    const int lrow = lane & 15;
    const int kgrp = lane >> 4;
    const unsigned short* wthi = Wthi + mat * LATENT * LATENT + ch * 64 * LATENT;
    const unsigned short* wtlo = Wtlo + mat * LATENT * LATENT + ch * 64 * LATENT;

    // ---- A fragments: 16 rows per wave, load fp32 + split hi/lo ----
    short8 ahi[4], alo[4];
    {
        int row = row0 + wid * 16 + lrow;
        if (row >= nNodes) row = nNodes - 1;      // clamped; writes are guarded
        const float* src = emb + (size_t)row * LATENT;
#pragma unroll
        for (int kk = 0; kk < 4; ++kk) {
            int chunk = kk * 4 + kgrp;
            float4 f0 = ((const float4*)(src + chunk * 8))[0];
            float4 f1 = ((const float4*)(src + chunk * 8))[1];
            float x[8] = {f0.x, f0.y, f0.z, f0.w, f1.x, f1.y, f1.z, f1.w};
            short8 h8, l8;
#pragma unroll
            for (int j = 0; j < 8; ++j) {
                unsigned short h = f2bf(x[j]);
                h8[j] = (short)h;
                l8[j] = (short)f2bf(x[j] - bf2f(h));
            }
            ahi[kk] = h8;
            alo[kk] = l8;
        }
    }

    floatx4 acc[4];
#pragma unroll
    for (int cb = 0; cb < 4; ++cb)
        acc[cb] = (floatx4){0.f, 0.f, 0.f, 0.f};

#pragma unroll
    for (int kk = 0; kk < 4; ++kk) {
        const int chunk = kk * 4 + kgrp;
#pragma unroll
        for (int cb = 0; cb < 4; ++cb) {
            int cl = cb * 16 + lrow;                  // local B row (0..63)
            short8 bhi = ((const short8*)(wthi + cl * LATENT))[chunk];
            acc[cb] = __builtin_amdgcn_mfma_f32_16x16x32_bf16(
                ahi[kk], bhi, acc[cb], 0, 0, 0);
            acc[cb] = __builtin_amdgcn_mfma_f32_16x16x32_bf16(
                alo[kk], bhi, acc[cb], 0, 0, 0);
            if (mat < 2) {
                short8 blo = ((const short8*)(wtlo + cl * LATENT))[chunk];
                acc[cb] = __builtin_amdgcn_mfma_f32_16x16x32_bf16(
                    ahi[kk], blo, acc[cb], 0, 0, 0);
            }
        }
    }

    // C/D layout: col = lane&15, row = (lane>>4)*4 + reg   [m89-verified]
#pragma unroll
    for (int cb = 0; cb < 4; ++cb)
#pragma unroll
        for (int i = 0; i < 4; ++i) {
            int row = row0 + wid * 16 + kgrp * 4 + i;
            int col = ch * 64 + cb * 16 + lrow;
            if (row < nNodes) {
                float v = acc[cb][i];
                if (mat == 0) {
                    Qf[(size_t)row * LATENT + col] = v;
                } else {
                    size_t base = (size_t)row * 256 + ((col >> 2) << 3)
                                  + (col & 3) + (mat == 1 ? 0 : 4);
                    KVb[base] = f2bf(v);
                }
            }
        }
}

// ---------------------------------------------------------------------------
// CSR build: histogram -> scan (2 kernels) -> scatter
// ---------------------------------------------------------------------------
__global__ __launch_bounds__(256) void count_deg(
    const int* __restrict__ rows, int* __restrict__ deg, int nE)
{
    int e = blockIdx.x * 256 + threadIdx.x;
    if (e < nE) atomicAdd(&deg[rows[e]], 1);
}

__global__ __launch_bounds__(SCAN_THREADS) void scan_block(
    const int* __restrict__ deg, int* __restrict__ excl,
    int* __restrict__ blockSums, int n)
{
    __shared__ int sSum[SCAN_THREADS];
    int tid  = threadIdx.x;
    int base = blockIdx.x * SCAN_BLOCK + tid * 8;
    int v[8];
    int tot = 0;
#pragma unroll
    for (int i = 0; i < 8; ++i) {
        int idx = base + i;
        v[i] = (idx < n) ? deg[idx] : 0;
        tot += v[i];
    }
    sSum[tid] = tot;
    __syncthreads();
    for (int off = 1; off < SCAN_THREADS; off <<= 1) {
        int x = (tid >= off) ? sSum[tid - off] : 0;
        __syncthreads();
        sSum[tid] += x;
        __syncthreads();
    }
    int run = (tid > 0) ? sSum[tid - 1] : 0;
#pragma unroll
    for (int i = 0; i < 8; ++i) {
        int idx = base + i;
        if (idx < n) excl[idx] = run;
        run += v[i];
    }
    if (tid == SCAN_THREADS - 1) blockSums[blockIdx.x] = sSum[SCAN_THREADS - 1];
}

// adds inline prefix of blockSums (nb <= 25) -- scan_top kernel eliminated
__global__ __launch_bounds__(256) void scan_add(
    const int* __restrict__ excl, const int* __restrict__ blockSums,
    int* __restrict__ start, int* __restrict__ cursor, int n)
{
    int i = blockIdx.x * 256 + threadIdx.x;
    if (i < n) {
        int nb = i / SCAN_BLOCK;
        int pre = 0;
        for (int j = 0; j < nb; ++j) pre += blockSums[j];
        int s = excl[i] + pre;
        start[i]  = s;
        cursor[i] = s;
    }
}

// writes packed (col, edge) pairs so the hot loop does ONE 8B load per edge
__global__ __launch_bounds__(256) void scatter_edges(
    const int* __restrict__ rows, const int* __restrict__ cols,
    int* __restrict__ cursor, int2* __restrict__ ce, int nE)
{
    int e = blockIdx.x * 256 + threadIdx.x;
    if (e < nE) {
        int p = atomicAdd(&cursor[rows[e]], 1);
        ce[p] = make_int2(cols[e], e);
    }
}

// ---------------------------------------------------------------------------
// Kernel 2: fused node-centric scores + aggregate (R10 form -- 28 VGPR).
// ONE 64-lane wave per node; halves split the edge list; lane t owns dims
// 4t..4t+3 (4 lanes/head). Per edge: one uint4 gather of packed {k4|v4};
// dot via 2x shfl_xor; __expf; accumulate. Writes rnArr for normalize_att.
// ---------------------------------------------------------------------------
__global__ __launch_bounds__(256) void node_fused(
    const float* __restrict__ Qf, const unsigned short* __restrict__ KVb,
    const int* __restrict__ start, const int* __restrict__ deg,
    const int2* __restrict__ ce,
    float* __restrict__ attOut,         // [E,8] <- exp (pre-normalization)
    float* __restrict__ rnArr,          // [N,8]
    float* __restrict__ outEmb, int nNodes)
{
    int node = blockIdx.x * 4 + (threadIdx.x >> 6);
    int lane = threadIdx.x & 63;
    int half = lane >> 5;
    int t    = lane & 31;               // lane owns dims 4t..4t+3
    if (node >= nNodes) return;
    int h = t >> 2;

    float4 q = ((const float4*)(Qf + (size_t)node * LATENT))[t];

    int s    = start[node];
    int cnt  = deg[node];
    int cnt2 = cnt >> 1;
    int jBeg = half ? cnt2 : 0;
    int jEnd = half ? cnt : cnt2;

    float4 acc = make_float4(0.f, 0.f, 0.f, 0.f);
    float norm = 0.f;

#define EDGE_BODY(E_, KV_)                                                     \
    {                                                                          \
        float p = q.x * bf2f((unsigned short)(KV_.x & 0xffff)) +               \
                  q.y * bf2f((unsigned short)(KV_.x >> 16)) +                  \
                  q.z * bf2f((unsigned short)(KV_.y & 0xffff)) +               \
                  q.w * bf2f((unsigned short)(KV_.y >> 16));                   \
        p += __shfl_xor(p, 1);                                                 \
        p += __shfl_xor(p, 2);                                                 \
        p = fminf(fmaxf(p, -10.f), 10.f);                                      \
        float ex = __expf(p);                                                  \
        if ((t & 3) == 0) attOut[(size_t)E_ * HEAD + h] = ex;                  \
        norm += ex;                                                            \
        acc.x += ex * bf2f((unsigned short)(KV_.z & 0xffff));                  \
        acc.y += ex * bf2f((unsigned short)(KV_.z >> 16));                     \
        acc.z += ex * bf2f((unsigned short)(KV_.w & 0xffff));                  \
        acc.w += ex * bf2f((unsigned short)(KV_.w >> 16));                     \
    }

    int j = jBeg;
    for (; j + 4 <= jEnd; j += 4) {
        int2 p0 = ce[s + j + 0];
        int2 p1 = ce[s + j + 1];
        int2 p2 = ce[s + j + 2];
        int2 p3 = ce[s + j + 3];
        uint4 kv0 = ((const uint4*)(KVb + (size_t)p0.x * 256))[t];
        uint4 kv1 = ((const uint4*)(KVb + (size_t)p1.x * 256))[t];
        uint4 kv2 = ((const uint4*)(KVb + (size_t)p2.x * 256))[t];
        uint4 kv3 = ((const uint4*)(KVb + (size_t)p3.x * 256))[t];
        EDGE_BODY(p0.y, kv0);
        EDGE_BODY(p1.y, kv1);
        EDGE_BODY(p2.y, kv2);
        EDGE_BODY(p3.y, kv3);
    }
    for (; j < jEnd; ++j) {
        int2 pp = ce[s + j];
        uint4 kv = ((const uint4*)(KVb + (size_t)pp.x * 256))[t];
        EDGE_BODY(pp.y, kv);
    }
#undef EDGE_BODY

    // combine halves
    norm  += __shfl_xor(norm, 32);
    acc.x += __shfl_xor(acc.x, 32);
    acc.y += __shfl_xor(acc.y, 32);
    acc.z += __shfl_xor(acc.z, 32);
    acc.w += __shfl_xor(acc.w, 32);

    float rn = 1.f / (norm + 1e-8f);
    if (half == 0) {
        acc.x *= rn; acc.y *= rn; acc.z *= rn; acc.w *= rn;
        ((float4*)(outEmb + (size_t)node * LATENT))[t] = acc;
        if ((t & 3) == 0) rnArr[node * HEAD + h] = rn;
    }
}

// ---------------------------------------------------------------------------
// Kernel 3: normalize att in place: att[e,h] = expAtt[e,h] * rn[rows[e],h]
// ---------------------------------------------------------------------------
__global__ __launch_bounds__(256) void normalize_att(
    const int* __restrict__ rows, const float* __restrict__ rnArr,
    float* __restrict__ att, int nEdges)
{
    int tIdx = blockIdx.x * 256 + threadIdx.x;
    int e = tIdx >> 3;
    int h = tIdx & 7;
    if (e >= nEdges) return;
    int r = rows[e];
    att[e * HEAD + h] *= rnArr[r * HEAD + h];
}

// ---------------------------------------------------------------------------
extern "C" void kernel_launch(void* const* d_in, const int* in_sizes, int n_in,
                              void* d_out, int out_size, void* d_ws, size_t ws_size,
                              hipStream_t stream)
{
    const float* emb  = (const float*)d_in[0];
    const int*   rows = (const int*)d_in[1];
    const int*   cols = (const int*)d_in[2];
    const float* Wq   = (const float*)d_in[3];
    const float* Wk   = (const float*)d_in[4];
    const float* Wv   = (const float*)d_in[5];

    const int N = in_sizes[0] / LATENT;   // 50000
    const int E = in_sizes[1];            // 800000

    float* outEmb = (float*)d_out;                         // [N,128]
    float* attOut = (float*)d_out + (size_t)N * LATENT;    // [E,8]

    float* Qf = (float*)d_ws;                              // [N,128] fp32
    unsigned short* KVb  = (unsigned short*)(Qf + (size_t)N * LATENT); // [N,256] packed
    unsigned short* Wthi = KVb + (size_t)N * 256;          // [3,128,128] bf16
    unsigned short* Wtlo = Wthi + 3 * LATENT * LATENT;
    float* rnArr   = (float*)(Wtlo + 3 * LATENT * LATENT); // [N,8]
    int* deg        = (int*)(rnArr + (size_t)N * HEAD);
    int* excl       = deg + N;
    int* startArr   = excl + N;
    int* cursor     = startArr + N;
    int* blockSums  = cursor + N;          // up to 64
    int2* ce        = (int2*)(blockSums + 64);   // [E] packed (col, edge)

    hipMemsetAsync(deg, 0, (size_t)N * sizeof(int), stream);

    // 0. split/transpose W
    convert_wt<<<(3 * LATENT * LATENT + 255) / 256, 256, 0, stream>>>(
        Wq, Wk, Wv, Wthi, Wtlo);

    // 1. QKV projections (LDS-free; 64x64 tiles; mat = y, col half = z)
    dim3 gGemm((N + 63) / 64, 3, 2);
    qkv_gemm_reg<<<gGemm, 256, 0, stream>>>(emb, Wthi, Wtlo, Qf, KVb, N);

    // 2. CSR build
    count_deg<<<(E + 255) / 256, 256, 0, stream>>>(rows, deg, E);
    int nb = (N + SCAN_BLOCK - 1) / SCAN_BLOCK;
    scan_block<<<nb, SCAN_THREADS, 0, stream>>>(deg, excl, blockSums, N);
    scan_add<<<(N + 255) / 256, 256, 0, stream>>>(excl, blockSums, startArr, cursor, N);
    scatter_edges<<<(E + 255) / 256, 256, 0, stream>>>(rows, cols, cursor, ce, E);

    // 3. fused scores + aggregate
    node_fused<<<(N + 3) / 4, 256, 0, stream>>>(Qf, KVb, startArr, deg, ce,
                                                attOut, rnArr, outEmb, N);

    // 4. normalize att in place (streaming)
    int tScores = E * HEAD;
    normalize_att<<<(tScores + 255) / 256, 256, 0, stream>>>(rows, rnArr, attOut, E);
}

// Round 14
// 203.026 us; speedup vs baseline: 1.3374x; 1.3374x over previous
//
#include <hip/hip_runtime.h>

#define LATENT 128
#define HEAD 8
#define DH 16
#define MAXD 64            // per-node LDS ex-buffer capacity (deg ~ Poisson(16))

#define SCAN_BLOCK 2048    // elements scanned per block
#define SCAN_THREADS 256   // 8 elements per thread

typedef __attribute__((ext_vector_type(8))) short short8;
typedef __attribute__((ext_vector_type(4))) float floatx4;

__device__ inline float bf2f(unsigned short u) {
    return __uint_as_float(((unsigned int)u) << 16);
}
__device__ inline unsigned short f2bf(float f) {
    unsigned int b = __float_as_uint(f);
    b += 0x7fffu + ((b >> 16) & 1u);          // RNE
    return (unsigned short)(b >> 16);
}

// ---------------------------------------------------------------------------
// Kernel 1: fused QKV projection + degree count.
// 1D grid: blocks [0,1152) do GEMM (decode: ch = b&1, mat = (b>>1)%3,
// bx = b/6 in [0,192)); blocks >= 1152 do count_deg (streaming, fills the
// CUs' latency gaps left by the GEMM blocks).
// GEMM block: converts its own fp32 W 64-col panel -> hi/lo bf16 in 32 KB LDS
// (once; kills the convert_wt kernel), then loops row-tiles tile = bx+192k
// barrier-free (B is read-only). Q,K: 3-term split-bf16 (fp32-accurate);
// V: 2-term. Output: Q fp32; K,V packed bf16 KV[node] = 32 x {k4|v4} chunks.
// ---------------------------------------------------------------------------
__global__ __launch_bounds__(256) void qkv_count(
    const float* __restrict__ emb,
    const float* __restrict__ Wq, const float* __restrict__ Wk, const float* __restrict__ Wv,
    float* __restrict__ Qf, unsigned short* __restrict__ KVb,
    const int* __restrict__ rows, int* __restrict__ deg,
    int nNodes, int nE, int nQkvBlocks)
{
    __shared__ unsigned short sBhi[64 * 128];   // 16 KB
    __shared__ unsigned short sBlo[64 * 128];   // 16 KB

    const int b = blockIdx.x;
    if (b >= nQkvBlocks) {                       // ---- count_deg part ----
        int e = (b - nQkvBlocks) * 256 + threadIdx.x;
        if (e < nE) atomicAdd(&deg[rows[e]], 1);
        return;
    }

    const int ch  = b & 1;                       // column half
    const int mat = (b >> 1) % 3;
    const int bx  = b / 6;                       // 0..191
    const float* W = (mat == 0) ? Wq : ((mat == 1) ? Wk : Wv);
    const int tid  = threadIdx.x;
    const int wid  = tid >> 6;
    const int lane = tid & 63;
    const int lrow = lane & 15;
    const int kgrp = lane >> 4;

    // ---- stage B: convert fp32 W[k][c] (c in [ch*64,+64)) -> hi/lo LDS ----
    // chunk g in [0,1024): cl = g>>4 (local col), ck = g&15 (8 k's per chunk)
#pragma unroll
    for (int it = 0; it < 4; ++it) {
        int g  = it * 256 + tid;
        int cl = g >> 4;
        int ck = g & 15;
        int c  = ch * 64 + cl;
        short8 h8, l8;
#pragma unroll
        for (int j = 0; j < 8; ++j) {
            float x = W[(ck * 8 + j) * LATENT + c];
            unsigned short h = f2bf(x);
            h8[j] = (short)h;
            l8[j] = (short)f2bf(x - bf2f(h));
        }
        int dst = cl * 16 + (ck ^ (cl & 7));
        ((short8*)sBhi)[dst] = h8;
        ((short8*)sBlo)[dst] = l8;
    }
    __syncthreads();

    const int nTiles = (nNodes + 63) >> 6;       // 782
    for (int tile = bx; tile < nTiles; tile += 192) {
        const int row0 = tile * 64;

        // ---- A fragments: 16 rows per wave, load fp32 + split hi/lo ----
        short8 ahi[4], alo[4];
        {
            int row = row0 + wid * 16 + lrow;
            if (row >= nNodes) row = nNodes - 1;     // clamped; writes guarded
            const float* src = emb + (size_t)row * LATENT;
#pragma unroll
            for (int kk = 0; kk < 4; ++kk) {
                int chunk = kk * 4 + kgrp;
                float4 f0 = ((const float4*)(src + chunk * 8))[0];
                float4 f1 = ((const float4*)(src + chunk * 8))[1];
                float x[8] = {f0.x, f0.y, f0.z, f0.w, f1.x, f1.y, f1.z, f1.w};
                short8 h8, l8;
#pragma unroll
                for (int j = 0; j < 8; ++j) {
                    unsigned short h = f2bf(x[j]);
                    h8[j] = (short)h;
                    l8[j] = (short)f2bf(x[j] - bf2f(h));
                }
                ahi[kk] = h8;
                alo[kk] = l8;
            }
        }

        floatx4 acc[4];
#pragma unroll
        for (int cb = 0; cb < 4; ++cb)
            acc[cb] = (floatx4){0.f, 0.f, 0.f, 0.f};

#pragma unroll
        for (int kk = 0; kk < 4; ++kk) {
            const int chunk = kk * 4 + kgrp;
#pragma unroll
            for (int cb = 0; cb < 4; ++cb) {
                int cl  = cb * 16 + lrow;
                int src = cl * 16 + (chunk ^ (cl & 7));
                short8 bhi = ((const short8*)sBhi)[src];
                acc[cb] = __builtin_amdgcn_mfma_f32_16x16x32_bf16(
                    ahi[kk], bhi, acc[cb], 0, 0, 0);
                acc[cb] = __builtin_amdgcn_mfma_f32_16x16x32_bf16(
                    alo[kk], bhi, acc[cb], 0, 0, 0);
                if (mat < 2) {
                    short8 blo = ((const short8*)sBlo)[src];
                    acc[cb] = __builtin_amdgcn_mfma_f32_16x16x32_bf16(
                        ahi[kk], blo, acc[cb], 0, 0, 0);
                }
            }
        }

        // C/D layout: col = lane&15, row = (lane>>4)*4 + reg  [m89-verified]
#pragma unroll
        for (int cb = 0; cb < 4; ++cb)
#pragma unroll
            for (int i = 0; i < 4; ++i) {
                int row = row0 + wid * 16 + kgrp * 4 + i;
                int col = ch * 64 + cb * 16 + lrow;
                if (row < nNodes) {
                    float v = acc[cb][i];
                    if (mat == 0) {
                        Qf[(size_t)row * LATENT + col] = v;
                    } else {
                        size_t base = (size_t)row * 256 + ((col >> 2) << 3)
                                      + (col & 3) + (mat == 1 ? 0 : 4);
                        KVb[base] = f2bf(v);
                    }
                }
            }
    }
}

// ---------------------------------------------------------------------------
// CSR: scan (2 kernels) -> scatter
// ---------------------------------------------------------------------------
__global__ __launch_bounds__(SCAN_THREADS) void scan_block(
    const int* __restrict__ deg, int* __restrict__ excl,
    int* __restrict__ blockSums, int n)
{
    __shared__ int sSum[SCAN_THREADS];
    int tid  = threadIdx.x;
    int base = blockIdx.x * SCAN_BLOCK + tid * 8;
    int v[8];
    int tot = 0;
#pragma unroll
    for (int i = 0; i < 8; ++i) {
        int idx = base + i;
        v[i] = (idx < n) ? deg[idx] : 0;
        tot += v[i];
    }
    sSum[tid] = tot;
    __syncthreads();
    for (int off = 1; off < SCAN_THREADS; off <<= 1) {
        int x = (tid >= off) ? sSum[tid - off] : 0;
        __syncthreads();
        sSum[tid] += x;
        __syncthreads();
    }
    int run = (tid > 0) ? sSum[tid - 1] : 0;
#pragma unroll
    for (int i = 0; i < 8; ++i) {
        int idx = base + i;
        if (idx < n) excl[idx] = run;
        run += v[i];
    }
    if (tid == SCAN_THREADS - 1) blockSums[blockIdx.x] = sSum[SCAN_THREADS - 1];
}

// adds inline prefix of blockSums (nb <= 25)
__global__ __launch_bounds__(256) void scan_add(
    const int* __restrict__ excl, const int* __restrict__ blockSums,
    int* __restrict__ start, int* __restrict__ cursor, int n)
{
    int i = blockIdx.x * 256 + threadIdx.x;
    if (i < n) {
        int nb = i / SCAN_BLOCK;
        int pre = 0;
        for (int j = 0; j < nb; ++j) pre += blockSums[j];
        int s = excl[i] + pre;
        start[i]  = s;
        cursor[i] = s;
    }
}

// writes packed (col, edge) pairs so the hot loop does ONE 8B load per edge
__global__ __launch_bounds__(256) void scatter_edges(
    const int* __restrict__ rows, const int* __restrict__ cols,
    int* __restrict__ cursor, int2* __restrict__ ce, int nE)
{
    int e = blockIdx.x * 256 + threadIdx.x;
    if (e < nE) {
        int p = atomicAdd(&cursor[rows[e]], 1);
        ce[p] = make_int2(cols[e], e);
    }
}

// ---------------------------------------------------------------------------
// Kernel 2: fused node-centric scores + aggregate + att write.
// ONE 64-lane wave per node; halves split the edge list; lane t owns dims
// 4t..4t+3 (4 lanes/head). Pass 1: gather packed {k4|v4}, dot via shfl_xor,
// __expf, accumulate; ex values buffered in LDS (deg<=64; else fallback
// writes attOut and RMWs later). Pass 2: att[e,h] = ex*rn written ONCE --
// the separate normalize_att kernel (51 MB of streaming traffic) is gone.
// ---------------------------------------------------------------------------
__global__ __launch_bounds__(256) void node_fused(
    const float* __restrict__ Qf, const unsigned short* __restrict__ KVb,
    const int* __restrict__ start, const int* __restrict__ deg,
    const int2* __restrict__ ce,
    float* __restrict__ attOut,         // [E,8] final normalized att
    float* __restrict__ outEmb, int nNodes)
{
    __shared__ float sEx[4][MAXD][HEAD];   // 8 KB
    __shared__ int   sE[4][MAXD];          // 1 KB

    int w    = threadIdx.x >> 6;
    int node = blockIdx.x * 4 + w;
    int lane = threadIdx.x & 63;
    int half = lane >> 5;
    int t    = lane & 31;               // lane owns dims 4t..4t+3
    int h    = t >> 2;
    bool valid = (node < nNodes);

    float4 q = make_float4(0.f, 0.f, 0.f, 0.f);
    int s = 0, cnt = 0;
    if (valid) {
        q   = ((const float4*)(Qf + (size_t)node * LATENT))[t];
        s   = start[node];
        cnt = deg[node];
    }
    bool fits = (cnt <= MAXD);

    int cnt2 = cnt >> 1;
    int jBeg = half ? cnt2 : 0;
    int jEnd = half ? cnt : cnt2;

    float4 acc = make_float4(0.f, 0.f, 0.f, 0.f);
    float norm = 0.f;

#define EDGE_BODY(J_, E_, KV_)                                                 \
    {                                                                          \
        float p = q.x * bf2f((unsigned short)(KV_.x & 0xffff)) +               \
                  q.y * bf2f((unsigned short)(KV_.x >> 16)) +                  \
                  q.z * bf2f((unsigned short)(KV_.y & 0xffff)) +               \
                  q.w * bf2f((unsigned short)(KV_.y >> 16));                   \
        p += __shfl_xor(p, 1);                                                 \
        p += __shfl_xor(p, 2);                                                 \
        p = fminf(fmaxf(p, -10.f), 10.f);                                      \
        float ex = __expf(p);                                                  \
        if (fits) {                                                            \
            if ((t & 3) == 0) sEx[w][J_][h] = ex;                              \
            if (t == 0) sE[w][J_] = E_;                                        \
        } else if ((t & 3) == 0) {                                             \
            attOut[(size_t)E_ * HEAD + h] = ex;                                \
        }                                                                      \
        norm += ex;                                                            \
        acc.x += ex * bf2f((unsigned short)(KV_.z & 0xffff));                  \
        acc.y += ex * bf2f((unsigned short)(KV_.z >> 16));                     \
        acc.z += ex * bf2f((unsigned short)(KV_.w & 0xffff));                  \
        acc.w += ex * bf2f((unsigned short)(KV_.w >> 16));                     \
    }

    int j = jBeg;
    for (; j + 4 <= jEnd; j += 4) {
        int2 p0 = ce[s + j + 0];
        int2 p1 = ce[s + j + 1];
        int2 p2 = ce[s + j + 2];
        int2 p3 = ce[s + j + 3];
        uint4 kv0 = ((const uint4*)(KVb + (size_t)p0.x * 256))[t];
        uint4 kv1 = ((const uint4*)(KVb + (size_t)p1.x * 256))[t];
        uint4 kv2 = ((const uint4*)(KVb + (size_t)p2.x * 256))[t];
        uint4 kv3 = ((const uint4*)(KVb + (size_t)p3.x * 256))[t];
        EDGE_BODY(j + 0, p0.y, kv0);
        EDGE_BODY(j + 1, p1.y, kv1);
        EDGE_BODY(j + 2, p2.y, kv2);
        EDGE_BODY(j + 3, p3.y, kv3);
    }
    for (; j < jEnd; ++j) {
        int2 pp = ce[s + j];
        uint4 kv = ((const uint4*)(KVb + (size_t)pp.x * 256))[t];
        EDGE_BODY(j, pp.y, kv);
    }
#undef EDGE_BODY

    // combine halves
    norm  += __shfl_xor(norm, 32);
    acc.x += __shfl_xor(acc.x, 32);
    acc.y += __shfl_xor(acc.y, 32);
    acc.z += __shfl_xor(acc.z, 32);
    acc.w += __shfl_xor(acc.w, 32);

    float rn = 1.f / (norm + 1e-8f);
    if (valid && half == 0) {
        float4 o = acc;
        o.x *= rn; o.y *= rn; o.z *= rn; o.w *= rn;
        ((float4*)(outEmb + (size_t)node * LATENT))[t] = o;
    }

    // ---- pass 2: write final att once (4 j-slots x 8 heads per half) ----
    __syncthreads();                     // order LDS ex/e stores (cross-lane)
    if (valid) {
        float rnH = __shfl(rn, (t & 7) << 2);
        if (fits) {
            for (int jj = jBeg + (t >> 3); jj < jEnd; jj += 4) {
                int e = sE[w][jj];
                attOut[(size_t)e * HEAD + (t & 7)] = sEx[w][jj][t & 7] * rnH;
            }
        } else {
            asm volatile("s_waitcnt vmcnt(0)" ::: "memory");
            for (int jj = jBeg + (t >> 3); jj < jEnd; jj += 4) {
                int e = ce[s + jj].y;
                attOut[(size_t)e * HEAD + (t & 7)] *= rnH;
            }
        }
    }
}

// ---------------------------------------------------------------------------
extern "C" void kernel_launch(void* const* d_in, const int* in_sizes, int n_in,
                              void* d_out, int out_size, void* d_ws, size_t ws_size,
                              hipStream_t stream)
{
    const float* emb  = (const float*)d_in[0];
    const int*   rows = (const int*)d_in[1];
    const int*   cols = (const int*)d_in[2];
    const float* Wq   = (const float*)d_in[3];
    const float* Wk   = (const float*)d_in[4];
    const float* Wv   = (const float*)d_in[5];

    const int N = in_sizes[0] / LATENT;   // 50000
    const int E = in_sizes[1];            // 800000

    float* outEmb = (float*)d_out;                         // [N,128]
    float* attOut = (float*)d_out + (size_t)N * LATENT;    // [E,8]

    float* Qf = (float*)d_ws;                              // [N,128] fp32
    unsigned short* KVb = (unsigned short*)(Qf + (size_t)N * LATENT); // [N,256]
    int* deg       = (int*)(KVb + (size_t)N * 256);
    int* excl      = deg + N;
    int* startArr  = excl + N;
    int* cursor    = startArr + N;
    int* blockSums = cursor + N;          // up to 64
    int2* ce       = (int2*)(blockSums + 64);   // [E] packed (col, edge)

    hipMemsetAsync(deg, 0, (size_t)N * sizeof(int), stream);

    // 1. fused QKV projection + degree histogram
    const int nQkvBlocks = 192 * 6;                 // 1152
    const int nCntBlocks = (E + 255) / 256;         // 3125
    qkv_count<<<nQkvBlocks + nCntBlocks, 256, 0, stream>>>(
        emb, Wq, Wk, Wv, Qf, KVb, rows, deg, N, E, nQkvBlocks);

    // 2. CSR scan + scatter
    int nb = (N + SCAN_BLOCK - 1) / SCAN_BLOCK;
    scan_block<<<nb, SCAN_THREADS, 0, stream>>>(deg, excl, blockSums, N);
    scan_add<<<(N + 255) / 256, 256, 0, stream>>>(excl, blockSums, startArr, cursor, N);
    scatter_edges<<<(E + 255) / 256, 256, 0, stream>>>(rows, cols, cursor, ce, E);

    // 3. fused scores + aggregate + att write
    node_fused<<<(N + 3) / 4, 256, 0, stream>>>(Qf, KVb, startArr, deg, ce,
                                                attOut, outEmb, N);
}